// Round 1
// baseline (550.424 us; speedup 1.0000x reference)
//
#include <hip/hip_runtime.h>
#include <math.h>

// Problem constants (from reference): B=128, FEW=64, D=512, E=16, O=512, H=64, K=3
constexpr int Bn  = 128;
constexpr int FEW = 64;
constexpr int Dd  = 512;
constexpr int En  = 16;
constexpr int On  = 512;
constexpr int Hn  = 64;
constexpr int Tn  = Bn * FEW;   // 8192 tokens

// Workspace layout (bytes):
//   topi : int  [Tn*4]        @ 0        (131072 B)  -- top-3 expert ids, slot 3 unused
//   topv : float[Tn*4]        @ 131072   (131072 B)  -- top-3 gate probs
//   A    : float[Bn*En*Hn]    @ 262144   (524288 B)  -- gate-weighted hidden accum
//   gsum : float[Bn*En]       @ 786432   (  8192 B)  -- gate mass per (batch, expert)

// ---------------------------------------------------------------------------
// K1: gating network. 256 blocks x 256 threads; block handles 32 tokens.
// Each wave handles 8 tokens, lane = hidden unit h (H=64 == wavefront size).
// gW1 staged through LDS in 4 chunks of 128 d-rows (32 KB each).
// ---------------------------------------------------------------------------
__global__ __launch_bounds__(256) void k_gate(
    const float* __restrict__ x, const float* __restrict__ gW1,
    const float* __restrict__ gb1, const float* __restrict__ gW2,
    const float* __restrict__ gb2, int* __restrict__ topi,
    float* __restrict__ topv)
{
    __shared__ float wlds[128 * 64];   // 32 KB: gW1 chunk [d][h]
    __shared__ float g1l[32 * 65];     // relu hidden per token (pad 65 vs bank stride)
    __shared__ float logl[32 * 17];    // logits per token (padded)
    __shared__ float w2l[64 * 16];     // gW2 staged
    __shared__ float b2l[16];

    const int tid = threadIdx.x;
    const int ln  = tid & 63;
    const int wv  = tid >> 6;
    const int t0  = blockIdx.x * 32;
    // wave-uniform first token of this wave -> scalar loads of x
    const int tw  = __builtin_amdgcn_readfirstlane(t0 + wv * 8);

    // stage gW2 (64x16 = 1024 floats) + gb2
    #pragma unroll
    for (int k = 0; k < 4; k++) w2l[tid + k * 256] = gW2[tid + k * 256];
    if (tid < 16) b2l[tid] = gb2[tid];

    float acc[8];
    const float gb1v = gb1[ln];
    #pragma unroll
    for (int i = 0; i < 8; i++) acc[i] = gb1v;

    for (int c = 0; c < 4; c++) {
        // stage gW1 rows [c*128, c*128+128): contiguous 8192 floats
        const float4* src = (const float4*)(gW1 + c * 8192);
        float4* dst = (float4*)wlds;
        #pragma unroll
        for (int k = 0; k < 8; k++) dst[tid + k * 256] = src[tid + k * 256];
        __syncthreads();
        for (int d = 0; d < 128; d += 4) {
            float4 xq[8];
            #pragma unroll
            for (int i = 0; i < 8; i++)
                xq[i] = *(const float4*)(x + (size_t)(tw + i) * Dd + c * 128 + d);
            #pragma unroll
            for (int dd = 0; dd < 4; dd++) {
                const float wvv = wlds[(d + dd) * 64 + ln];
                #pragma unroll
                for (int i = 0; i < 8; i++)
                    acc[i] = fmaf(((const float*)&xq[i])[dd], wvv, acc[i]);
            }
        }
        __syncthreads();
    }
    // relu -> LDS
    #pragma unroll
    for (int i = 0; i < 8; i++) g1l[(wv * 8 + i) * 65 + ln] = fmaxf(acc[i], 0.f);
    __syncthreads();

    // logits: 32 tokens x 16 experts = 512, two per thread
    #pragma unroll
    for (int q = 0; q < 2; q++) {
        const int lid = tid * 2 + q;
        const int tok = lid >> 4;
        const int e   = lid & 15;
        float s = b2l[e];
        const float* g = &g1l[tok * 65];
        #pragma unroll 8
        for (int h = 0; h < 64; h++) s = fmaf(g[h], w2l[h * 16 + e], s);
        logl[tok * 17 + e] = s;
    }
    __syncthreads();

    // softmax + top-3 (ties -> lowest index, matching lax.top_k stability)
    if (tid < 32) {
        float v[16];
        float mx = -1e30f;
        #pragma unroll
        for (int e = 0; e < 16; e++) { v[e] = logl[tid * 17 + e]; mx = fmaxf(mx, v[e]); }
        float ssum = 0.f;
        #pragma unroll
        for (int e = 0; e < 16; e++) { v[e] = __expf(v[e] - mx); ssum += v[e]; }
        const float inv = 1.f / ssum;
        #pragma unroll
        for (int e = 0; e < 16; e++) v[e] *= inv;
        const int t = t0 + tid;
        unsigned mask = 0;
        for (int j = 0; j < 3; j++) {
            float bv = -1.f; int bi = 0;
            for (int e = 0; e < 16; e++) {
                if (!(mask & (1u << e)) && v[e] > bv) { bv = v[e]; bi = e; }
            }
            mask |= (1u << bi);
            topi[t * 4 + j] = bi;
            topv[t * 4 + j] = bv;
        }
    }
}

// ---------------------------------------------------------------------------
// K2: sparse expert fc1 + gate-weighted accumulation.
// Grid 256 = 16 experts x 16 token-slices of 512. Block (e, s) owns
// A[b, e, :] for the 8 batches b in its slice -> plain stores, no atomics.
// W1[e] staged through LDS in 4 chunks of 32 KB; 8 tokens per wave so each
// LDS weight read feeds 8 FMAs.
// ---------------------------------------------------------------------------
__global__ __launch_bounds__(256) void k_expert(
    const float* __restrict__ x, const float* __restrict__ W1,
    const float* __restrict__ b1, const int* __restrict__ topi,
    const float* __restrict__ topv, float* __restrict__ A,
    float* __restrict__ gsum)
{
    __shared__ float wlds[128 * 64];   // 32 KB chunk of W1[e]
    __shared__ int   lt[512];          // compacted local token ids
    __shared__ float lv[512];          // their gate values
    __shared__ float Ap[8 * 64];       // A partial [batch_local][h]
    __shared__ float gp[8];            // gate-mass partial per batch_local
    __shared__ int   cnt;

    const int tid = threadIdx.x;
    const int ln  = tid & 63;
    const int wv  = tid >> 6;
    const int e   = blockIdx.x >> 4;   // expert
    const int s   = blockIdx.x & 15;   // token slice
    const int ts  = s * 512;

    if (tid == 0) cnt = 0;
    #pragma unroll
    for (int k = tid; k < 512; k += 256) Ap[k] = 0.f;
    if (tid < 8) gp[tid] = 0.f;
    __syncthreads();

    // compact tokens in this slice that selected expert e
    for (int to = tid; to < 512; to += 256) {
        const int t = ts + to;
        const int4   ti = *(const int4*)(topi + t * 4);
        const float4 tv = *(const float4*)(topv + t * 4);
        const int   idx[3] = { ti.x, ti.y, ti.z };
        const float val[3] = { tv.x, tv.y, tv.z };
        #pragma unroll
        for (int j = 0; j < 3; j++) {
            if (idx[j] == e) {
                const int p = atomicAdd(&cnt, 1);
                lt[p] = to;
                lv[p] = val[j];
                atomicAdd(&gp[to >> 6], val[j]);
            }
        }
    }
    __syncthreads();
    const int n = cnt;

    const float b1v = b1[e * 64 + ln];
    const float* W1e = W1 + (size_t)e * (Dd * Hn);

    for (int r0 = 0; r0 < n; r0 += 32) {       // n is block-uniform
        const int base = r0 + wv * 8;
        int mt[8]; float mv[8];
        #pragma unroll
        for (int i = 0; i < 8; i++) {
            const int p = base + i;
            if (p < n) { mt[i] = lt[p]; mv[i] = lv[p]; }
            else       { mt[i] = 0;     mv[i] = 0.f;  }
            mt[i] = __builtin_amdgcn_readfirstlane(mt[i]);  // wave-uniform -> s_loads
        }
        float acc[8];
        #pragma unroll
        for (int i = 0; i < 8; i++) acc[i] = 0.f;

        for (int c = 0; c < 4; c++) {
            __syncthreads();   // wlds reuse guard
            const float4* src = (const float4*)(W1e + c * 8192);
            float4* dst = (float4*)wlds;
            #pragma unroll
            for (int k = 0; k < 8; k++) dst[tid + k * 256] = src[tid + k * 256];
            __syncthreads();
            for (int d = 0; d < 128; d += 4) {
                float4 xq[8];
                #pragma unroll
                for (int i = 0; i < 8; i++)
                    xq[i] = *(const float4*)(x + (size_t)(ts + mt[i]) * Dd + c * 128 + d);
                #pragma unroll
                for (int dd = 0; dd < 4; dd++) {
                    const float wvv = wlds[(d + dd) * 64 + ln];
                    #pragma unroll
                    for (int i = 0; i < 8; i++)
                        acc[i] = fmaf(((const float*)&xq[i])[dd], wvv, acc[i]);
                }
            }
        }
        // relu, gate-weight, accumulate into LDS partial
        #pragma unroll
        for (int i = 0; i < 8; i++) {
            const float h = fmaxf(acc[i] + b1v, 0.f);
            atomicAdd(&Ap[(mt[i] >> 6) * 64 + ln], mv[i] * h);
        }
    }
    __syncthreads();

    // write A / gsum (sole owner of these (b, e) entries; covers poison)
    for (int k = tid; k < 512; k += 256) {
        const int bl = k >> 6, h = k & 63;
        A[(size_t)(s * 8 + bl) * (En * Hn) + e * 64 + h] = Ap[k];
    }
    if (tid < 8) gsum[(s * 8 + tid) * En + e] = gp[tid];
}

// ---------------------------------------------------------------------------
// K3: out[b, o] = (A[b] . W2 + gsum[b] . b2) / 64
// Grid 128 = 64 batch-pairs x 2 column-halves (halves W2 re-read traffic).
// ---------------------------------------------------------------------------
__global__ __launch_bounds__(256) void k_out(
    const float* __restrict__ W2, const float* __restrict__ b2,
    const float* __restrict__ A, const float* __restrict__ gsum,
    float* __restrict__ out)
{
    __shared__ float Al[2048];   // A for 2 batches
    __shared__ float gl[32];

    const int tid = threadIdx.x;
    const int bp  = blockIdx.x >> 1;
    const int hf  = blockIdx.x & 1;
    const int b0  = bp << 1;

    #pragma unroll
    for (int k = 0; k < 2; k++)
        ((float4*)Al)[tid + k * 256] = ((const float4*)(A + (size_t)b0 * 1024))[tid + k * 256];
    if (tid < 32) gl[tid] = gsum[b0 * En + tid];
    __syncthreads();

    const int o = hf * 256 + tid;
    float a0 = 0.f, a1 = 0.f;
    for (int eh = 0; eh < 1024; eh++) {
        const float w = W2[(size_t)eh * On + o];
        a0 = fmaf(Al[eh], w, a0);
        a1 = fmaf(Al[1024 + eh], w, a1);
    }
    #pragma unroll
    for (int e = 0; e < 16; e++) {
        const float w = b2[e * On + o];
        a0 = fmaf(gl[e], w, a0);
        a1 = fmaf(gl[16 + e], w, a1);
    }
    constexpr float sc = 1.f / 64.f;
    out[(size_t)b0 * On + o]       = a0 * sc;
    out[(size_t)(b0 + 1) * On + o] = a1 * sc;
}

// ---------------------------------------------------------------------------
extern "C" void kernel_launch(void* const* d_in, const int* in_sizes, int n_in,
                              void* d_out, int out_size, void* d_ws, size_t ws_size,
                              hipStream_t stream)
{
    (void)in_sizes; (void)n_in; (void)out_size; (void)ws_size;
    const float* x   = (const float*)d_in[0];
    const float* gW1 = (const float*)d_in[1];
    const float* gb1 = (const float*)d_in[2];
    const float* gW2 = (const float*)d_in[3];
    const float* gb2 = (const float*)d_in[4];
    const float* W1  = (const float*)d_in[5];
    const float* b1  = (const float*)d_in[6];
    const float* W2  = (const float*)d_in[7];
    const float* b2  = (const float*)d_in[8];
    float* out = (float*)d_out;

    char* ws = (char*)d_ws;
    int*   topi = (int*)(ws);
    float* topv = (float*)(ws + 131072);
    float* A    = (float*)(ws + 262144);
    float* gsum = (float*)(ws + 786432);

    k_gate  <<<dim3(256), dim3(256), 0, stream>>>(x, gW1, gb1, gW2, gb2, topi, topv);
    k_expert<<<dim3(256), dim3(256), 0, stream>>>(x, W1, b1, topi, topv, A, gsum);
    k_out   <<<dim3(128), dim3(256), 0, stream>>>(W2, b2, A, gsum, out);
}

// Round 2
// 245.497 us; speedup vs baseline: 2.2421x; 2.2421x over previous
//
#include <hip/hip_runtime.h>
#include <math.h>

// Problem constants: B=128, FEW=64, D=512, E=16, O=512, H=64, K=3
constexpr int Bn  = 128;
constexpr int FEW = 64;
constexpr int Dd  = 512;
constexpr int En  = 16;
constexpr int On  = 512;
constexpr int Hn  = 64;
constexpr int Tn  = Bn * FEW;   // 8192 tokens

// Workspace layout (bytes):
//   topi : int  [Tn*4]        @ 0        -- top-3 expert ids (slot 3 unused)
//   topv : float[Tn*4]        @ 131072   -- top-3 gate probs
//   A    : float[Bn*En*Hn]    @ 262144   -- gate-weighted hidden accum
//   gsum : float[Bn*En]       @ 786432   -- gate mass per (batch, expert)

// ---------------------------------------------------------------------------
// K1: gating. 512 blocks x 256 threads; block = 16 tokens, wave = 4 tokens.
// gW1 read directly per-lane (L2-resident, 128 KB); x loads wave-uniform.
// Software-pipelined d-loop (double-buffer, groups of 8), no barriers inside.
// ---------------------------------------------------------------------------
__global__ __launch_bounds__(256) void k_gate(
    const float* __restrict__ x, const float* __restrict__ gW1,
    const float* __restrict__ gb1, const float* __restrict__ gW2,
    const float* __restrict__ gb2, int* __restrict__ topi,
    float* __restrict__ topv)
{
    __shared__ float g1l[16 * 65];    // relu hidden per token (padded)
    __shared__ float logl[16 * 17];   // logits per token (padded)
    __shared__ float w2l[64 * 16];
    __shared__ float b2l[16];

    const int tid = threadIdx.x;
    const int ln  = tid & 63;
    const int wv  = tid >> 6;
    const int t0  = blockIdx.x * 16;
    const int tw  = __builtin_amdgcn_readfirstlane(t0 + wv * 4);

    #pragma unroll
    for (int k = 0; k < 4; k++) w2l[tid + k * 256] = gW2[tid + k * 256];
    if (tid < 16) b2l[tid] = gb2[tid];

    float acc[4];
    const float gb1v = gb1[ln];
    #pragma unroll
    for (int i = 0; i < 4; i++) acc[i] = gb1v;

    const float* xt0 = x + (size_t)tw * Dd;

    // pipeline prologue: group 0 (d = 0..7)
    float  wc[8];
    float4 xa[4], xb[4];
    #pragma unroll
    for (int j = 0; j < 8; j++) wc[j] = gW1[j * 64 + ln];
    #pragma unroll
    for (int i = 0; i < 4; i++) {
        xa[i] = *(const float4*)(xt0 + i * Dd);
        xb[i] = *(const float4*)(xt0 + i * Dd + 4);
    }

    for (int d = 0; d < 512; d += 8) {
        const int dn = (d + 8) & 511;          // branch-free wrap for tail prefetch
        float  wn[8];
        float4 xc[4], xd[4];
        #pragma unroll
        for (int j = 0; j < 8; j++) wn[j] = gW1[(dn + j) * 64 + ln];
        #pragma unroll
        for (int i = 0; i < 4; i++) {
            xc[i] = *(const float4*)(xt0 + i * Dd + dn);
            xd[i] = *(const float4*)(xt0 + i * Dd + dn + 4);
        }
        #pragma unroll
        for (int j = 0; j < 4; j++)
            #pragma unroll
            for (int i = 0; i < 4; i++)
                acc[i] = fmaf(((const float*)&xa[i])[j], wc[j], acc[i]);
        #pragma unroll
        for (int j = 0; j < 4; j++)
            #pragma unroll
            for (int i = 0; i < 4; i++)
                acc[i] = fmaf(((const float*)&xb[i])[j], wc[j + 4], acc[i]);
        #pragma unroll
        for (int j = 0; j < 8; j++) wc[j] = wn[j];
        #pragma unroll
        for (int i = 0; i < 4; i++) { xa[i] = xc[i]; xb[i] = xd[i]; }
    }

    #pragma unroll
    for (int i = 0; i < 4; i++) g1l[(wv * 4 + i) * 65 + ln] = fmaxf(acc[i], 0.f);
    __syncthreads();

    // logits: 16 tokens x 16 experts = 256 -> one per thread
    {
        const int tok = tid >> 4;
        const int e   = tid & 15;
        float s = b2l[e];
        const float* g = &g1l[tok * 65];
        #pragma unroll 8
        for (int h = 0; h < 64; h++) s = fmaf(g[h], w2l[h * 16 + e], s);
        logl[tok * 17 + e] = s;
    }
    __syncthreads();

    // softmax + top-3 (strict > keeps lowest index on ties, matching lax.top_k)
    if (tid < 16) {
        float v[16];
        float mx = -1e30f;
        #pragma unroll
        for (int e = 0; e < 16; e++) { v[e] = logl[tid * 17 + e]; mx = fmaxf(mx, v[e]); }
        float ssum = 0.f;
        #pragma unroll
        for (int e = 0; e < 16; e++) { v[e] = __expf(v[e] - mx); ssum += v[e]; }
        const float inv = 1.f / ssum;
        #pragma unroll
        for (int e = 0; e < 16; e++) v[e] *= inv;
        const int t = t0 + tid;
        unsigned mask = 0;
        for (int j = 0; j < 3; j++) {
            float bv = -1.f; int bi = 0;
            for (int e = 0; e < 16; e++) {
                if (!(mask & (1u << e)) && v[e] > bv) { bv = v[e]; bi = e; }
            }
            mask |= (1u << bi);
            topi[t * 4 + j] = bi;
            topv[t * 4 + j] = bv;
        }
    }
}

// ---------------------------------------------------------------------------
// K2: sparse expert fc1 + gate-weighted accumulation.
// Grid 1024 = 16 experts x 64 slices of 128 tokens (2 batches). Block (e,s)
// owns A[2s..2s+1, e, :] -> plain stores. W1[e] read directly per-lane from
// L2 (no LDS staging, no barriers in main loop). Wave = 8 tokens,
// double-buffered d-loop in groups of 4.
// ---------------------------------------------------------------------------
__global__ __launch_bounds__(256) void k_expert(
    const float* __restrict__ x, const float* __restrict__ W1,
    const float* __restrict__ b1, const int* __restrict__ topi,
    const float* __restrict__ topv, float* __restrict__ A,
    float* __restrict__ gsum)
{
    __shared__ int   lt[128];
    __shared__ float lv[128];
    __shared__ float Ap[2 * 64];
    __shared__ float gp[2];
    __shared__ int   cnt;

    const int tid = threadIdx.x;
    const int ln  = tid & 63;
    const int wv  = tid >> 6;
    const int e   = blockIdx.x >> 6;    // expert 0..15
    const int s   = blockIdx.x & 63;    // slice 0..63
    const int ts  = s * 128;

    if (tid == 0) cnt = 0;
    if (tid < 128) Ap[tid] = 0.f;
    if (tid < 2) gp[tid] = 0.f;
    __syncthreads();

    if (tid < 128) {
        const int t = ts + tid;
        const int4   ti = *(const int4*)(topi + t * 4);
        const float4 tv = *(const float4*)(topv + t * 4);
        const int   idx[3] = { ti.x, ti.y, ti.z };
        const float val[3] = { tv.x, tv.y, tv.z };
        #pragma unroll
        for (int j = 0; j < 3; j++) {
            if (idx[j] == e) {
                const int p = atomicAdd(&cnt, 1);
                lt[p] = tid;
                lv[p] = val[j];
                atomicAdd(&gp[tid >> 6], val[j]);
            }
        }
    }
    __syncthreads();
    const int n = cnt;

    const float b1v = b1[e * 64 + ln];
    const float* __restrict__ W1e = W1 + (size_t)e * (Dd * Hn);

    for (int r0 = wv * 8; r0 < n; r0 += 32) {   // per-wave stride; empty waves skip
        const float* xt[8];
        float mvv[8];
        int   bl[8];
        #pragma unroll
        for (int i = 0; i < 8; i++) {
            const int p = r0 + i;
            int   t = (p < n) ? lt[p] : 0;
            float v = (p < n) ? lv[p] : 0.f;
            t = __builtin_amdgcn_readfirstlane(t);   // wave-uniform -> scalar addr
            xt[i]  = x + (size_t)(ts + t) * Dd;
            mvv[i] = v;
            bl[i]  = t >> 6;
        }
        float acc[8];
        #pragma unroll
        for (int i = 0; i < 8; i++) acc[i] = 0.f;

        // pipeline prologue: group d = 0..3
        float  wc[4];
        float4 xc[8];
        #pragma unroll
        for (int j = 0; j < 4; j++) wc[j] = W1e[j * 64 + ln];
        #pragma unroll
        for (int i = 0; i < 8; i++) xc[i] = *(const float4*)(xt[i]);

        for (int d = 0; d < 512; d += 4) {
            const int dn = (d + 4) & 511;
            float  wn[4];
            float4 xn[8];
            #pragma unroll
            for (int j = 0; j < 4; j++) wn[j] = W1e[(dn + j) * 64 + ln];
            #pragma unroll
            for (int i = 0; i < 8; i++) xn[i] = *(const float4*)(xt[i] + dn);
            #pragma unroll
            for (int j = 0; j < 4; j++)
                #pragma unroll
                for (int i = 0; i < 8; i++)
                    acc[i] = fmaf(((const float*)&xc[i])[j], wc[j], acc[i]);
            #pragma unroll
            for (int j = 0; j < 4; j++) wc[j] = wn[j];
            #pragma unroll
            for (int i = 0; i < 8; i++) xc[i] = xn[i];
        }

        #pragma unroll
        for (int i = 0; i < 8; i++) {
            const float h = fmaxf(acc[i] + b1v, 0.f);
            atomicAdd(&Ap[bl[i] * 64 + ln], mvv[i] * h);
        }
    }
    __syncthreads();

    // sole owner of (2s..2s+1, e) -> plain stores (also covers ws poison)
    if (tid < 128) {
        const int bl2 = tid >> 6, h = tid & 63;
        A[(size_t)(s * 2 + bl2) * (En * Hn) + e * 64 + h] = Ap[tid];
    }
    if (tid < 2) gsum[(s * 2 + tid) * En + e] = gp[tid];
}

// ---------------------------------------------------------------------------
// K3: out[b, o] = (A[b] . W2 + gsum[b] . b2) / 64
// Grid 256 = 32 batch-quads x 8 column-octs (64 cols). 4 batches share each
// W2 slice (64 MB total L2 traffic). Double-buffered eh-loop, groups of 8.
// ---------------------------------------------------------------------------
__global__ __launch_bounds__(256) void k_out(
    const float* __restrict__ W2, const float* __restrict__ b2,
    const float* __restrict__ A, const float* __restrict__ gsum,
    float* __restrict__ out)
{
    __shared__ float Al[4096];   // A for 4 batches
    __shared__ float gl[64];

    const int tid = threadIdx.x;
    const int bq  = blockIdx.x >> 3;       // 0..31
    const int oc  = blockIdx.x & 7;        // 0..7
    const int b0  = bq * 4;
    const int bh  = tid >> 6;              // which of 4 batches
    const int o   = oc * 64 + (tid & 63);

    #pragma unroll
    for (int k = 0; k < 4; k++)
        ((float4*)Al)[tid + k * 256] = ((const float4*)(A + (size_t)b0 * 1024))[tid + k * 256];
    if (tid < 64) gl[tid] = gsum[b0 * En + tid];
    __syncthreads();

    const int ab = bh * 1024;
    float a = 0.f;
    const float* w2p = W2 + o;

    float wc[8];
    #pragma unroll
    for (int j = 0; j < 8; j++) wc[j] = w2p[j * On];

    for (int eh = 0; eh < 1024; eh += 8) {
        const int en = (eh + 8) & 1023;
        float wn[8];
        #pragma unroll
        for (int j = 0; j < 8; j++) wn[j] = w2p[(size_t)(en + j) * On];
        #pragma unroll
        for (int j = 0; j < 8; j++) a = fmaf(Al[ab + eh + j], wc[j], a);
        #pragma unroll
        for (int j = 0; j < 8; j++) wc[j] = wn[j];
    }
    #pragma unroll
    for (int ee = 0; ee < 16; ee++) a = fmaf(gl[bh * 16 + ee], b2[ee * On + o], a);

    out[(size_t)(b0 + bh) * On + o] = a * (1.f / 64.f);
}

// ---------------------------------------------------------------------------
extern "C" void kernel_launch(void* const* d_in, const int* in_sizes, int n_in,
                              void* d_out, int out_size, void* d_ws, size_t ws_size,
                              hipStream_t stream)
{
    (void)in_sizes; (void)n_in; (void)out_size; (void)ws_size;
    const float* x   = (const float*)d_in[0];
    const float* gW1 = (const float*)d_in[1];
    const float* gb1 = (const float*)d_in[2];
    const float* gW2 = (const float*)d_in[3];
    const float* gb2 = (const float*)d_in[4];
    const float* W1  = (const float*)d_in[5];
    const float* b1  = (const float*)d_in[6];
    const float* W2  = (const float*)d_in[7];
    const float* b2  = (const float*)d_in[8];
    float* out = (float*)d_out;

    char* ws = (char*)d_ws;
    int*   topi = (int*)(ws);
    float* topv = (float*)(ws + 131072);
    float* A    = (float*)(ws + 262144);
    float* gsum = (float*)(ws + 786432);

    k_gate  <<<dim3(512),  dim3(256), 0, stream>>>(x, gW1, gb1, gW2, gb2, topi, topv);
    k_expert<<<dim3(1024), dim3(256), 0, stream>>>(x, W1, b1, topi, topv, A, gsum);
    k_out   <<<dim3(256),  dim3(256), 0, stream>>>(W2, b2, A, gsum, out);
}